// Round 22
// baseline (114.826 us; speedup 1.0000x reference)
//
#include <hip/hip_runtime.h>
#include <hip/hip_bf16.h>
#include <stdint.h>
#include <math.h>

#define H_HT 26
#define W_HT 122
#define NPIX (H_HT * W_HT)   // 3172
#define NA 60
#define NR 125
#define NB 32
#define NC 4
#define NBC (NB * NC)        // 128
#define PH 288
#define PW 800
#define NSPLIT 16            // rho splits per angle; wave bins r = q*4+w + 64t
#define PIX_PT 13            // ceil(3172/256) pixels per thread in csr

#define TR_BLKS (H_HT * 8)   // 208 transpose blocks: (h, 16-bc group)
#define ZERO_BLKS 4
#define HB (NA * NSPLIT)     // 960 hough blocks
#define L1_BLKS 120
#define K2_BLKS (HB + L1_BLKS)   // 1080 total
#define SHARD_SZ 30
#define NSHARD (K2_BLKS / SHARD_SZ)   // 36 (exact)

// ---- workspace layout (bytes, tight pack, 64B aligned) ----
#define WS_OFF   0                         // int32 [60*126]          30240
#define WS_LIST  30272                     // uint16[60*3172]        380640
#define WS_PREDT 410944                    // float [3172*128]      1624064
#define WS_PVP   2035008                   // u64   [128*60]          61440
#define WS_L1    2096448                   // float [128*4*125]      256000
#define WS_CNT   2352448                   // u32   [NSHARD+1]          148

// ---------------- Kernel A: fused setup (R14/R18-validated logic) -----------
__global__ __launch_bounds__(256) void setup(const float* __restrict__ pred,
                                             int* __restrict__ off,
                                             uint16_t* __restrict__ list,
                                             float* __restrict__ pred_T,
                                             unsigned long long* __restrict__ pvp,
                                             unsigned int* __restrict__ cnt) {
    const int tid = threadIdx.x;
    if (blockIdx.x < NA) {
        const int a = blockIdx.x;
        __shared__ int s_cnt[NR];
        __shared__ int sc[2][NR];
        __shared__ int s_pre[NR + 1];
        __shared__ int s_cur[NR];

        double t  = __dmul_rn((double)(a * 3), 0.017453292519943295);
        double cs = cos(t);
        double sn = sin(t);

        int rloc[PIX_PT];
#pragma unroll
        for (int k = 0; k < PIX_PT; ++k) {
            int p = tid + k * 256;
            rloc[k] = 0;
            if (p < NPIX) {
                int h = p / W_HT;
                int w = p - h * W_HT;
                double xs = (double)w - 60.5;
                double ys = (double)h - 12.5;
                double rho = __dadd_rn(__dmul_rn(xs, cs), __dmul_rn(ys, sn));
                int r = (int)rint(rho) + NR / 2;
                r = r < 0 ? 0 : (r > NR - 1 ? NR - 1 : r);
                rloc[k] = r;
            }
        }
        for (int i = tid; i < NR; i += 256) s_cnt[i] = 0;
        __syncthreads();
#pragma unroll
        for (int k = 0; k < PIX_PT; ++k) {
            int p = tid + k * 256;
            if (p < NPIX) atomicAdd(&s_cnt[rloc[k]], 1);
        }
        __syncthreads();
        if (tid < NR) sc[0][tid] = s_cnt[tid];
        __syncthreads();
        int pin = 0;
        for (int d = 1; d < NR; d <<= 1) {
            if (tid < NR) {
                int v = sc[pin][tid];
                if (tid >= d) v += sc[pin][tid - d];
                sc[pin ^ 1][tid] = v;
            }
            __syncthreads();
            pin ^= 1;
        }
        if (tid == 0) s_pre[0] = 0;
        if (tid < NR) s_pre[tid + 1] = sc[pin][tid];
        __syncthreads();
        for (int r = tid; r < NR + 1; r += 256) off[a * (NR + 1) + r] = s_pre[r];
        for (int r = tid; r < NR; r += 256) s_cur[r] = s_pre[r];
        __syncthreads();
#pragma unroll
        for (int k = 0; k < PIX_PT; ++k) {
            int p = tid + k * 256;
            if (p < NPIX) {
                int slot = atomicAdd(&s_cur[rloc[k]], 1);
                list[a * NPIX + slot] = (uint16_t)p;
            }
        }
    } else if (blockIdx.x < NA + TR_BLKS) {
        const int bidx = blockIdx.x - NA;
        const int h    = bidx >> 3;        // 0..25
        const int g    = bidx & 7;         // 0..7
        const int bc0  = g * 16;
        __shared__ float s_row[16][802];
        const float C1 = (float)(288.0 / 26.0);
        const float C2 = (float)(800.0 / 122.0);
        const int hi = (int)floorf((float)h * C1);
        for (int i = tid; i < 16 * 200; i += 256) {
            int j  = i / 200;
            int c4 = i - j * 200;
            const float4* rp = reinterpret_cast<const float4*>(
                pred + ((size_t)(bc0 + j) * PH + hi) * PW);
            float4 v = rp[c4];
            s_row[j][c4 * 4 + 0] = v.x;
            s_row[j][c4 * 4 + 1] = v.y;
            s_row[j][c4 * 4 + 2] = v.z;
            s_row[j][c4 * 4 + 3] = v.w;
        }
        __syncthreads();
        for (int idx = tid; idx < W_HT * 16; idx += 256) {
            int w = idx >> 4;              // 0..121
            int j = idx & 15;
            int wi = (int)floorf((float)w * C2);
            pred_T[(size_t)(h * W_HT + w) * NBC + bc0 + j] = s_row[j][wi];
        }
    } else {
        int bz = blockIdx.x - NA - TR_BLKS;
        int i0 = bz * 256 + tid;
        for (int i = i0; i < NA * NBC; i += ZERO_BLKS * 256) pvp[i] = 0ull;
        if (bz == 0 && tid <= NSHARD) cnt[tid] = 0u;
    }
}

// ---------------- Kernel B: hough (R18 T7) + L1 workers + sharded tail ------
__global__ __launch_bounds__(256) void hough_l1_loss(const float* __restrict__ pred_T,
                                                     const int* __restrict__ off,
                                                     const uint16_t* __restrict__ list,
                                                     unsigned long long* __restrict__ pvp,
                                                     float* __restrict__ L1t,
                                                     unsigned int* __restrict__ cnt,
                                                     const float* __restrict__ ht,
                                                     const float* __restrict__ pexist,
                                                     float* __restrict__ out) {
    __shared__ uint16_t s_list[NPIX];    // 6344 B
    __shared__ int      s_off[NR + 1];
    __shared__ float    s_v[4][32][4];
    __shared__ int      s_i[4][32][4];

    const int tid = threadIdx.x;

    if (blockIdx.x < HB) {
        // ---------- hough float4 quad-lanes (R18-validated, verbatim) ------
        const int blk  = blockIdx.x;
        const int a    = blk / NSPLIT;
        const int q    = blk - a * NSPLIT;
        const int w    = tid >> 6;
        const int lane = tid & 63;
        const int li   = lane & 31;
        const int hw8  = (lane >> 5) * 8;

        {
            const uint32_t* src = reinterpret_cast<const uint32_t*>(list + a * NPIX);
            uint32_t* dst = reinterpret_cast<uint32_t*>(s_list);
            for (int i = tid; i < NPIX / 2; i += 256) dst[i] = src[i];
            for (int r = tid; r < NR + 1; r += 256) s_off[r] = off[a * (NR + 1) + r];
        }
        __syncthreads();

        const float4* pT4 = reinterpret_cast<const float4*>(pred_T);
        float bvx = -1.0f, bvy = -1.0f, bvz = -1.0f, bvw = -1.0f;
        int   bix = 0, biy = 0, biz = 0, biw = 0;
        for (int r = q * 4 + w; r < NR; r += 64) {
            const int o0 = s_off[r];
            const int o1 = s_off[r + 1];
            float4 c0 = {0,0,0,0}, c1 = {0,0,0,0}, c2 = {0,0,0,0}, c3 = {0,0,0,0};
            float4 c4 = {0,0,0,0}, c5 = {0,0,0,0}, c6 = {0,0,0,0}, c7 = {0,0,0,0};
            for (int j = o0; j < o1; j += 16) {
                int base = j + hw8;
                int i0 = base, i1 = base + 1, i2 = base + 2, i3 = base + 3;
                int i4 = base + 4, i5 = base + 5, i6 = base + 6, i7 = base + 7;
                float m0 = (i0 < o1) ? 1.0f : 0.0f;
                float m1 = (i1 < o1) ? 1.0f : 0.0f;
                float m2 = (i2 < o1) ? 1.0f : 0.0f;
                float m3 = (i3 < o1) ? 1.0f : 0.0f;
                float m4 = (i4 < o1) ? 1.0f : 0.0f;
                float m5 = (i5 < o1) ? 1.0f : 0.0f;
                float m6 = (i6 < o1) ? 1.0f : 0.0f;
                float m7 = (i7 < o1) ? 1.0f : 0.0f;
                int p0 = s_list[i0 < o1 ? i0 : o0];
                int p1 = s_list[i1 < o1 ? i1 : o0];
                int p2 = s_list[i2 < o1 ? i2 : o0];
                int p3 = s_list[i3 < o1 ? i3 : o0];
                int p4 = s_list[i4 < o1 ? i4 : o0];
                int p5 = s_list[i5 < o1 ? i5 : o0];
                int p6 = s_list[i6 < o1 ? i6 : o0];
                int p7 = s_list[i7 < o1 ? i7 : o0];
                float4 v0 = pT4[p0 * 32 + li];
                float4 v1 = pT4[p1 * 32 + li];
                float4 v2 = pT4[p2 * 32 + li];
                float4 v3 = pT4[p3 * 32 + li];
                float4 v4 = pT4[p4 * 32 + li];
                float4 v5 = pT4[p5 * 32 + li];
                float4 v6 = pT4[p6 * 32 + li];
                float4 v7 = pT4[p7 * 32 + li];
                c0.x = fmaf(v0.x, m0, c0.x); c0.y = fmaf(v0.y, m0, c0.y);
                c0.z = fmaf(v0.z, m0, c0.z); c0.w = fmaf(v0.w, m0, c0.w);
                c1.x = fmaf(v1.x, m1, c1.x); c1.y = fmaf(v1.y, m1, c1.y);
                c1.z = fmaf(v1.z, m1, c1.z); c1.w = fmaf(v1.w, m1, c1.w);
                c2.x = fmaf(v2.x, m2, c2.x); c2.y = fmaf(v2.y, m2, c2.y);
                c2.z = fmaf(v2.z, m2, c2.z); c2.w = fmaf(v2.w, m2, c2.w);
                c3.x = fmaf(v3.x, m3, c3.x); c3.y = fmaf(v3.y, m3, c3.y);
                c3.z = fmaf(v3.z, m3, c3.z); c3.w = fmaf(v3.w, m3, c3.w);
                c4.x = fmaf(v4.x, m4, c4.x); c4.y = fmaf(v4.y, m4, c4.y);
                c4.z = fmaf(v4.z, m4, c4.z); c4.w = fmaf(v4.w, m4, c4.w);
                c5.x = fmaf(v5.x, m5, c5.x); c5.y = fmaf(v5.y, m5, c5.y);
                c5.z = fmaf(v5.z, m5, c5.z); c5.w = fmaf(v5.w, m5, c5.w);
                c6.x = fmaf(v6.x, m6, c6.x); c6.y = fmaf(v6.y, m6, c6.y);
                c6.z = fmaf(v6.z, m6, c6.z); c6.w = fmaf(v6.w, m6, c6.w);
                c7.x = fmaf(v7.x, m7, c7.x); c7.y = fmaf(v7.y, m7, c7.y);
                c7.z = fmaf(v7.z, m7, c7.z); c7.w = fmaf(v7.w, m7, c7.w);
            }
            float sx = ((c0.x + c1.x) + (c2.x + c3.x)) + ((c4.x + c5.x) + (c6.x + c7.x));
            float sy = ((c0.y + c1.y) + (c2.y + c3.y)) + ((c4.y + c5.y) + (c6.y + c7.y));
            float sz = ((c0.z + c1.z) + (c2.z + c3.z)) + ((c4.z + c5.z) + (c6.z + c7.z));
            float sw = ((c0.w + c1.w) + (c2.w + c3.w)) + ((c4.w + c5.w) + (c6.w + c7.w));
            sx += __shfl_xor(sx, 32);
            sy += __shfl_xor(sy, 32);
            sz += __shfl_xor(sz, 32);
            sw += __shfl_xor(sw, 32);
            int gbin = a * NR + r;
            if (sx > bvx) { bvx = sx; bix = gbin; }
            if (sy > bvy) { bvy = sy; biy = gbin; }
            if (sz > bvz) { bvz = sz; biz = gbin; }
            if (sw > bvw) { bvw = sw; biw = gbin; }
        }
        if (hw8 == 0) {
            s_v[w][li][0] = bvx; s_i[w][li][0] = bix;
            s_v[w][li][1] = bvy; s_i[w][li][1] = biy;
            s_v[w][li][2] = bvz; s_i[w][li][2] = biz;
            s_v[w][li][3] = bvw; s_i[w][li][3] = biw;
        }
        __syncthreads();
        if (tid < 32) {
#pragma unroll
            for (int comp = 0; comp < 4; ++comp) {
                float m = s_v[0][tid][comp];
                int   jb = s_i[0][tid][comp];
#pragma unroll
                for (int ww = 1; ww < 4; ++ww) {
                    float ov = s_v[ww][tid][comp];
                    int   oi = s_i[ww][tid][comp];
                    if (ov > m || (ov == m && oi < jb)) { m = ov; jb = oi; }
                }
                unsigned long long e = ((unsigned long long)__float_as_uint(m < 0.f ? 0.f : m) << 32)
                                     | (unsigned long long)(65535 - jb);
                atomicMax(&pvp[(4 * tid + comp) * NA + a], e);
            }
        }
    } else {
        // ---------- L1 workers: L1t[(b*4+c)*125+r] = sum_a |ht[...]| -------
        const int i = blockIdx.x - HB;
        for (int e = i * 256 + tid; e < NBC * NR; e += L1_BLKS * 256) {
            int cr = e / NR;               // (b*4+c)
            int r  = e - cr * NR;
            const float* base = ht + (size_t)cr * NA * NR + r;
            float s = 0.0f;
            for (int a = 0; a < NA; ++a) s += fabsf(base[a * NR]);
            L1t[e] = s;
        }
    }

    // ---- sharded last-arriver (no single-address storm; deadlock-free) ----
    __shared__ int s_last;
    __threadfence();
    __syncthreads();
    if (tid == 0) {
        s_last = 0;
        int shard = blockIdx.x / SHARD_SZ;        // 0..NSHARD-1, exact split
        unsigned int o1 = atomicAdd(&cnt[shard], 1u);
        if (o1 == (unsigned int)(SHARD_SZ - 1)) {
            __threadfence();                       // order shard obs -> root add
            unsigned int o2 = atomicAdd(&cnt[NSHARD], 1u);
            if (o2 == (unsigned int)(NSHARD - 1)) s_last = 1;
        }
    }
    __syncthreads();
    if (!s_last) return;
    __threadfence();   // acquire: see all pvp atomicMax + L1t stores

    __shared__ int   s_fidx[NBC];
    __shared__ float s_t[512];

    if (tid < NBC) {   // per (b,k): argmax over 60 angles (packed-u64 max)
        unsigned long long be = 0ull;
        const unsigned long long* pr = pvp + (size_t)tid * NA;
        for (int aa = 0; aa < NA; ++aa) {
            unsigned long long e = pr[aa];
            if (e > be) be = e;
        }
        s_fidx[tid] = 65535 - (int)(be & 0xFFFFull);
    }
    __syncthreads();

#pragma unroll
    for (int it = 0; it < 2; ++it) {
        int T = tid + 256 * it;           // task = (b, c, k)
        int b = T >> 4;
        int combo = T & 15;
        int c = combo >> 2;
        int k = combo & 3;
        int fidx = s_fidx[b * 4 + k];
        int a0 = fidx / NR;
        int r  = fidx - a0 * NR;
        int cr = b * 4 + c;
        float l1 = fmaxf(L1t[cr * NR + r], 1e-12f);
        float gg = ht[((size_t)cr * NA + a0) * NR + r] / l1;
        float ex = (pexist[b * 4 + k] > 0.9f) ? 1.0f : 0.0f;
        s_t[T] = -logf(gg + 1e-12f) * ex;
    }
    __syncthreads();
    if (tid < NB) {    // deterministic per-b serial 16-sum
        float s = 0.0f;
        for (int i2 = 0; i2 < 16; ++i2) s += s_t[tid * 16 + i2];
        out[tid] = s * (1.0f / 16.0f);
    }
}

extern "C" void kernel_launch(void* const* d_in, const int* in_sizes, int n_in,
                              void* d_out, int out_size, void* d_ws, size_t ws_size,
                              hipStream_t stream) {
    const float* ht     = (const float*)d_in[0];
    const float* pred   = (const float*)d_in[1];
    const float* pexist = (const float*)d_in[2];

    char* ws = (char*)d_ws;
    int*      off    = (int*)     (ws + WS_OFF);
    uint16_t* list   = (uint16_t*)(ws + WS_LIST);
    float*    pred_T = (float*)   (ws + WS_PREDT);
    unsigned long long* pvp = (unsigned long long*)(ws + WS_PVP);
    float*    L1t    = (float*)   (ws + WS_L1);
    unsigned int* cnt = (unsigned int*)(ws + WS_CNT);

    setup<<<NA + TR_BLKS + ZERO_BLKS, 256, 0, stream>>>(pred, off, list, pred_T, pvp, cnt);
    hough_l1_loss<<<K2_BLKS, 256, 0, stream>>>(pred_T, off, list, pvp, L1t, cnt,
                                               ht, pexist, (float*)d_out);
}

// Round 23
// 36.952 us; speedup vs baseline: 3.1074x; 3.1074x over previous
//
#include <hip/hip_runtime.h>
#include <hip/hip_bf16.h>
#include <stdint.h>
#include <math.h>

#define H_HT 26
#define W_HT 122
#define NPIX (H_HT * W_HT)   // 3172
#define NA 60
#define NR 125
#define NB 32
#define NC 4
#define NBC (NB * NC)        // 128
#define PH 288
#define PW 800
#define NSPLIT 16            // rho splits per angle; wave bins r = q*4+w + 64t
#define PIX_PT 13            // ceil(3172/256) pixels per thread in csr

#define TR_BLKS (H_HT * 8)   // 208 transpose blocks: (h, 16-bc group)
#define ZERO_BLKS 4
#define HB (NA * NSPLIT)     // 960 hough blocks
#define L1_BLKS 120
#define K2_BLKS (HB + L1_BLKS)   // 1080 total

// ---- workspace layout (bytes, tight pack, 64B aligned) ----
#define WS_OFF   0                         // int32 [60*126]          30240
#define WS_LIST  30272                     // uint16[60*3172]        380640
#define WS_PREDT 410944                    // float [3172*128]      1624064
#define WS_PVP   2035008                   // u64   [128*60]          61440
#define WS_L1    2096448                   // float [128*4*125]      256000
#define WS_CNT   2352448                   // u32 arrival counter

// ---------------- Kernel A: fused setup (R14/R18-validated logic) -----------
__global__ __launch_bounds__(256) void setup(const float* __restrict__ pred,
                                             int* __restrict__ off,
                                             uint16_t* __restrict__ list,
                                             float* __restrict__ pred_T,
                                             unsigned long long* __restrict__ pvp,
                                             unsigned int* __restrict__ cnt) {
    const int tid = threadIdx.x;
    if (blockIdx.x < NA) {
        const int a = blockIdx.x;
        __shared__ int s_cnt[NR];
        __shared__ int sc[2][NR];
        __shared__ int s_pre[NR + 1];
        __shared__ int s_cur[NR];

        double t  = __dmul_rn((double)(a * 3), 0.017453292519943295);
        double cs = cos(t);
        double sn = sin(t);

        int rloc[PIX_PT];
#pragma unroll
        for (int k = 0; k < PIX_PT; ++k) {
            int p = tid + k * 256;
            rloc[k] = 0;
            if (p < NPIX) {
                int h = p / W_HT;
                int w = p - h * W_HT;
                double xs = (double)w - 60.5;
                double ys = (double)h - 12.5;
                double rho = __dadd_rn(__dmul_rn(xs, cs), __dmul_rn(ys, sn));
                int r = (int)rint(rho) + NR / 2;
                r = r < 0 ? 0 : (r > NR - 1 ? NR - 1 : r);
                rloc[k] = r;
            }
        }
        for (int i = tid; i < NR; i += 256) s_cnt[i] = 0;
        __syncthreads();
#pragma unroll
        for (int k = 0; k < PIX_PT; ++k) {
            int p = tid + k * 256;
            if (p < NPIX) atomicAdd(&s_cnt[rloc[k]], 1);
        }
        __syncthreads();
        if (tid < NR) sc[0][tid] = s_cnt[tid];
        __syncthreads();
        int pin = 0;
        for (int d = 1; d < NR; d <<= 1) {
            if (tid < NR) {
                int v = sc[pin][tid];
                if (tid >= d) v += sc[pin][tid - d];
                sc[pin ^ 1][tid] = v;
            }
            __syncthreads();
            pin ^= 1;
        }
        if (tid == 0) s_pre[0] = 0;
        if (tid < NR) s_pre[tid + 1] = sc[pin][tid];
        __syncthreads();
        for (int r = tid; r < NR + 1; r += 256) off[a * (NR + 1) + r] = s_pre[r];
        for (int r = tid; r < NR; r += 256) s_cur[r] = s_pre[r];
        __syncthreads();
#pragma unroll
        for (int k = 0; k < PIX_PT; ++k) {
            int p = tid + k * 256;
            if (p < NPIX) {
                int slot = atomicAdd(&s_cur[rloc[k]], 1);
                list[a * NPIX + slot] = (uint16_t)p;
            }
        }
    } else if (blockIdx.x < NA + TR_BLKS) {
        const int bidx = blockIdx.x - NA;
        const int h    = bidx >> 3;        // 0..25
        const int g    = bidx & 7;         // 0..7
        const int bc0  = g * 16;
        __shared__ float s_row[16][802];
        const float C1 = (float)(288.0 / 26.0);
        const float C2 = (float)(800.0 / 122.0);
        const int hi = (int)floorf((float)h * C1);
        for (int i = tid; i < 16 * 200; i += 256) {
            int j  = i / 200;
            int c4 = i - j * 200;
            const float4* rp = reinterpret_cast<const float4*>(
                pred + ((size_t)(bc0 + j) * PH + hi) * PW);
            float4 v = rp[c4];
            s_row[j][c4 * 4 + 0] = v.x;
            s_row[j][c4 * 4 + 1] = v.y;
            s_row[j][c4 * 4 + 2] = v.z;
            s_row[j][c4 * 4 + 3] = v.w;
        }
        __syncthreads();
        for (int idx = tid; idx < W_HT * 16; idx += 256) {
            int w = idx >> 4;              // 0..121
            int j = idx & 15;
            int wi = (int)floorf((float)w * C2);
            pred_T[(size_t)(h * W_HT + w) * NBC + bc0 + j] = s_row[j][wi];
        }
    } else {
        int bz = blockIdx.x - NA - TR_BLKS;
        int i0 = bz * 256 + tid;
        for (int i = i0; i < NA * NBC; i += ZERO_BLKS * 256) pvp[i] = 0ull;
        if (bz == 0 && tid == 0) cnt[0] = 0u;
    }
}

// ---------------- Kernel B: hough (R18 T7) + L1 workers + fence-free tail ---
__global__ __launch_bounds__(256) void hough_l1_loss(const float* __restrict__ pred_T,
                                                     const int* __restrict__ off,
                                                     const uint16_t* __restrict__ list,
                                                     unsigned long long* __restrict__ pvp,
                                                     float* __restrict__ L1t,
                                                     unsigned int* __restrict__ cnt,
                                                     const float* __restrict__ ht,
                                                     const float* __restrict__ pexist,
                                                     float* __restrict__ out) {
    __shared__ uint16_t s_list[NPIX];    // 6344 B
    __shared__ int      s_off[NR + 1];
    __shared__ float    s_v[4][32][4];
    __shared__ int      s_i[4][32][4];

    const int tid = threadIdx.x;

    if (blockIdx.x < HB) {
        // ---------- hough float4 quad-lanes (R18-validated, verbatim) ------
        const int blk  = blockIdx.x;
        const int a    = blk / NSPLIT;
        const int q    = blk - a * NSPLIT;
        const int w    = tid >> 6;
        const int lane = tid & 63;
        const int li   = lane & 31;
        const int hw8  = (lane >> 5) * 8;

        {
            const uint32_t* src = reinterpret_cast<const uint32_t*>(list + a * NPIX);
            uint32_t* dst = reinterpret_cast<uint32_t*>(s_list);
            for (int i = tid; i < NPIX / 2; i += 256) dst[i] = src[i];
            for (int r = tid; r < NR + 1; r += 256) s_off[r] = off[a * (NR + 1) + r];
        }
        __syncthreads();

        const float4* pT4 = reinterpret_cast<const float4*>(pred_T);
        float bvx = -1.0f, bvy = -1.0f, bvz = -1.0f, bvw = -1.0f;
        int   bix = 0, biy = 0, biz = 0, biw = 0;
        for (int r = q * 4 + w; r < NR; r += 64) {
            const int o0 = s_off[r];
            const int o1 = s_off[r + 1];
            float4 c0 = {0,0,0,0}, c1 = {0,0,0,0}, c2 = {0,0,0,0}, c3 = {0,0,0,0};
            float4 c4 = {0,0,0,0}, c5 = {0,0,0,0}, c6 = {0,0,0,0}, c7 = {0,0,0,0};
            for (int j = o0; j < o1; j += 16) {
                int base = j + hw8;
                int i0 = base, i1 = base + 1, i2 = base + 2, i3 = base + 3;
                int i4 = base + 4, i5 = base + 5, i6 = base + 6, i7 = base + 7;
                float m0 = (i0 < o1) ? 1.0f : 0.0f;
                float m1 = (i1 < o1) ? 1.0f : 0.0f;
                float m2 = (i2 < o1) ? 1.0f : 0.0f;
                float m3 = (i3 < o1) ? 1.0f : 0.0f;
                float m4 = (i4 < o1) ? 1.0f : 0.0f;
                float m5 = (i5 < o1) ? 1.0f : 0.0f;
                float m6 = (i6 < o1) ? 1.0f : 0.0f;
                float m7 = (i7 < o1) ? 1.0f : 0.0f;
                int p0 = s_list[i0 < o1 ? i0 : o0];
                int p1 = s_list[i1 < o1 ? i1 : o0];
                int p2 = s_list[i2 < o1 ? i2 : o0];
                int p3 = s_list[i3 < o1 ? i3 : o0];
                int p4 = s_list[i4 < o1 ? i4 : o0];
                int p5 = s_list[i5 < o1 ? i5 : o0];
                int p6 = s_list[i6 < o1 ? i6 : o0];
                int p7 = s_list[i7 < o1 ? i7 : o0];
                float4 v0 = pT4[p0 * 32 + li];
                float4 v1 = pT4[p1 * 32 + li];
                float4 v2 = pT4[p2 * 32 + li];
                float4 v3 = pT4[p3 * 32 + li];
                float4 v4 = pT4[p4 * 32 + li];
                float4 v5 = pT4[p5 * 32 + li];
                float4 v6 = pT4[p6 * 32 + li];
                float4 v7 = pT4[p7 * 32 + li];
                c0.x = fmaf(v0.x, m0, c0.x); c0.y = fmaf(v0.y, m0, c0.y);
                c0.z = fmaf(v0.z, m0, c0.z); c0.w = fmaf(v0.w, m0, c0.w);
                c1.x = fmaf(v1.x, m1, c1.x); c1.y = fmaf(v1.y, m1, c1.y);
                c1.z = fmaf(v1.z, m1, c1.z); c1.w = fmaf(v1.w, m1, c1.w);
                c2.x = fmaf(v2.x, m2, c2.x); c2.y = fmaf(v2.y, m2, c2.y);
                c2.z = fmaf(v2.z, m2, c2.z); c2.w = fmaf(v2.w, m2, c2.w);
                c3.x = fmaf(v3.x, m3, c3.x); c3.y = fmaf(v3.y, m3, c3.y);
                c3.z = fmaf(v3.z, m3, c3.z); c3.w = fmaf(v3.w, m3, c3.w);
                c4.x = fmaf(v4.x, m4, c4.x); c4.y = fmaf(v4.y, m4, c4.y);
                c4.z = fmaf(v4.z, m4, c4.z); c4.w = fmaf(v4.w, m4, c4.w);
                c5.x = fmaf(v5.x, m5, c5.x); c5.y = fmaf(v5.y, m5, c5.y);
                c5.z = fmaf(v5.z, m5, c5.z); c5.w = fmaf(v5.w, m5, c5.w);
                c6.x = fmaf(v6.x, m6, c6.x); c6.y = fmaf(v6.y, m6, c6.y);
                c6.z = fmaf(v6.z, m6, c6.z); c6.w = fmaf(v6.w, m6, c6.w);
                c7.x = fmaf(v7.x, m7, c7.x); c7.y = fmaf(v7.y, m7, c7.y);
                c7.z = fmaf(v7.z, m7, c7.z); c7.w = fmaf(v7.w, m7, c7.w);
            }
            float sx = ((c0.x + c1.x) + (c2.x + c3.x)) + ((c4.x + c5.x) + (c6.x + c7.x));
            float sy = ((c0.y + c1.y) + (c2.y + c3.y)) + ((c4.y + c5.y) + (c6.y + c7.y));
            float sz = ((c0.z + c1.z) + (c2.z + c3.z)) + ((c4.z + c5.z) + (c6.z + c7.z));
            float sw = ((c0.w + c1.w) + (c2.w + c3.w)) + ((c4.w + c5.w) + (c6.w + c7.w));
            sx += __shfl_xor(sx, 32);
            sy += __shfl_xor(sy, 32);
            sz += __shfl_xor(sz, 32);
            sw += __shfl_xor(sw, 32);
            int gbin = a * NR + r;
            if (sx > bvx) { bvx = sx; bix = gbin; }
            if (sy > bvy) { bvy = sy; biy = gbin; }
            if (sz > bvz) { bvz = sz; biz = gbin; }
            if (sw > bvw) { bvw = sw; biw = gbin; }
        }
        if (hw8 == 0) {
            s_v[w][li][0] = bvx; s_i[w][li][0] = bix;
            s_v[w][li][1] = bvy; s_i[w][li][1] = biy;
            s_v[w][li][2] = bvz; s_i[w][li][2] = biz;
            s_v[w][li][3] = bvw; s_i[w][li][3] = biw;
        }
        __syncthreads();
        if (tid < 32) {
#pragma unroll
            for (int comp = 0; comp < 4; ++comp) {
                float m = s_v[0][tid][comp];
                int   jb = s_i[0][tid][comp];
#pragma unroll
                for (int ww = 1; ww < 4; ++ww) {
                    float ov = s_v[ww][tid][comp];
                    int   oi = s_i[ww][tid][comp];
                    if (ov > m || (ov == m && oi < jb)) { m = ov; jb = oi; }
                }
                unsigned long long e = ((unsigned long long)__float_as_uint(m < 0.f ? 0.f : m) << 32)
                                     | (unsigned long long)(65535 - jb);
                atomicMax(&pvp[(4 * tid + comp) * NA + a], e);
            }
        }
    } else {
        // ---------- L1 workers: device-coherent atomic stores --------------
        const int i = blockIdx.x - HB;
        for (int e = i * 256 + tid; e < NBC * NR; e += L1_BLKS * 256) {
            int cr = e / NR;               // (b*4+c)
            int r  = e - cr * NR;
            const float* base = ht + (size_t)cr * NA * NR + r;
            float s = 0.0f;
            for (int a = 0; a < NA; ++a) s += fabsf(base[a * NR]);
            atomicExch(&L1t[e], s);        // coherent-point write, no fence
        }
    }

    // ---- fence-free arrival: drain wave VMEM, barrier, single counter ----
    __shared__ int s_last;
    asm volatile("s_waitcnt vmcnt(0)" ::: "memory");  // atomics complete @ coherent point
    __syncthreads();
    if (tid == 0)
        s_last = (atomicAdd(cnt, 1u) == (unsigned int)(K2_BLKS - 1)) ? 1 : 0;
    __syncthreads();
    if (!s_last) return;
    __threadfence();   // tail-only acquire (single block, cheap)

    __shared__ int   s_fidx[NBC];
    __shared__ float s_t[512];

    if (tid < NBC) {   // per (b,k): argmax over 60 angles (packed-u64 max)
        unsigned long long be = 0ull;
        const unsigned long long* pr = pvp + (size_t)tid * NA;
        for (int aa = 0; aa < NA; ++aa) {
            unsigned long long e = pr[aa];
            if (e > be) be = e;
        }
        s_fidx[tid] = 65535 - (int)(be & 0xFFFFull);
    }
    __syncthreads();

#pragma unroll
    for (int it = 0; it < 2; ++it) {
        int T = tid + 256 * it;           // task = (b, c, k)
        int b = T >> 4;
        int combo = T & 15;
        int c = combo >> 2;
        int k = combo & 3;
        int fidx = s_fidx[b * 4 + k];
        int a0 = fidx / NR;
        int r  = fidx - a0 * NR;
        int cr = b * 4 + c;
        float l1 = fmaxf(L1t[cr * NR + r], 1e-12f);
        float gg = ht[((size_t)cr * NA + a0) * NR + r] / l1;
        float ex = (pexist[b * 4 + k] > 0.9f) ? 1.0f : 0.0f;
        s_t[T] = -logf(gg + 1e-12f) * ex;
    }
    __syncthreads();
    if (tid < NB) {    // deterministic per-b serial 16-sum
        float s = 0.0f;
        for (int i2 = 0; i2 < 16; ++i2) s += s_t[tid * 16 + i2];
        out[tid] = s * (1.0f / 16.0f);
    }
}

extern "C" void kernel_launch(void* const* d_in, const int* in_sizes, int n_in,
                              void* d_out, int out_size, void* d_ws, size_t ws_size,
                              hipStream_t stream) {
    const float* ht     = (const float*)d_in[0];
    const float* pred   = (const float*)d_in[1];
    const float* pexist = (const float*)d_in[2];

    char* ws = (char*)d_ws;
    int*      off    = (int*)     (ws + WS_OFF);
    uint16_t* list   = (uint16_t*)(ws + WS_LIST);
    float*    pred_T = (float*)   (ws + WS_PREDT);
    unsigned long long* pvp = (unsigned long long*)(ws + WS_PVP);
    float*    L1t    = (float*)   (ws + WS_L1);
    unsigned int* cnt = (unsigned int*)(ws + WS_CNT);

    setup<<<NA + TR_BLKS + ZERO_BLKS, 256, 0, stream>>>(pred, off, list, pred_T, pvp, cnt);
    hough_l1_loss<<<K2_BLKS, 256, 0, stream>>>(pred_T, off, list, pvp, L1t, cnt,
                                               ht, pexist, (float*)d_out);
}

// Round 24
// 31.305 us; speedup vs baseline: 3.6680x; 1.1804x over previous
//
#include <hip/hip_runtime.h>
#include <hip/hip_bf16.h>
#include <stdint.h>
#include <math.h>

#define H_HT 26
#define W_HT 122
#define NPIX (H_HT * W_HT)   // 3172
#define NA 60
#define NR 125
#define NB 32
#define NC 4
#define NBC (NB * NC)        // 128
#define PH 288
#define PW 800
#define NSPLIT 16            // rho splits per angle; wave bins r = q*4+w + 64t
#define PIX_PT 13            // ceil(3172/256) pixels per thread in csr

#define TR_BLKS (H_HT * 8)   // 208 transpose blocks: (h, 16-bc group)
#define ZERO_BLKS 4
#define HB (NA * NSPLIT)     // 960 hough blocks
#define L1_BLKS 120
#define K2_BLKS (HB + L1_BLKS)   // 1080 total
#define SHARD_SZ 30
#define NSHARD (K2_BLKS / SHARD_SZ)   // 36 (exact)
#define CNT_STRIDE 16                 // u32 stride = 64B (one cache line per shard)

// ---- workspace layout (bytes, tight pack, 64B aligned) ----
#define WS_OFF   0                         // int32 [60*126]          30240
#define WS_LIST  30272                     // uint16[60*3172]        380640
#define WS_PREDT 410944                    // float [3172*128]      1624064
#define WS_PVP   2035008                   // u64   [128*60]          61440
#define WS_L1    2096448                   // float [128*4*125]      256000
#define WS_CNT   2352448                   // u32   [(NSHARD+1)*16]    2368

// ---------------- Kernel A: fused setup (R14/R18-validated logic) -----------
__global__ __launch_bounds__(256) void setup(const float* __restrict__ pred,
                                             int* __restrict__ off,
                                             uint16_t* __restrict__ list,
                                             float* __restrict__ pred_T,
                                             unsigned long long* __restrict__ pvp,
                                             unsigned int* __restrict__ cnt) {
    const int tid = threadIdx.x;
    if (blockIdx.x < NA) {
        const int a = blockIdx.x;
        __shared__ int s_cnt[NR];
        __shared__ int sc[2][NR];
        __shared__ int s_pre[NR + 1];
        __shared__ int s_cur[NR];

        double t  = __dmul_rn((double)(a * 3), 0.017453292519943295);
        double cs = cos(t);
        double sn = sin(t);

        int rloc[PIX_PT];
#pragma unroll
        for (int k = 0; k < PIX_PT; ++k) {
            int p = tid + k * 256;
            rloc[k] = 0;
            if (p < NPIX) {
                int h = p / W_HT;
                int w = p - h * W_HT;
                double xs = (double)w - 60.5;
                double ys = (double)h - 12.5;
                double rho = __dadd_rn(__dmul_rn(xs, cs), __dmul_rn(ys, sn));
                int r = (int)rint(rho) + NR / 2;
                r = r < 0 ? 0 : (r > NR - 1 ? NR - 1 : r);
                rloc[k] = r;
            }
        }
        for (int i = tid; i < NR; i += 256) s_cnt[i] = 0;
        __syncthreads();
#pragma unroll
        for (int k = 0; k < PIX_PT; ++k) {
            int p = tid + k * 256;
            if (p < NPIX) atomicAdd(&s_cnt[rloc[k]], 1);
        }
        __syncthreads();
        if (tid < NR) sc[0][tid] = s_cnt[tid];
        __syncthreads();
        int pin = 0;
        for (int d = 1; d < NR; d <<= 1) {
            if (tid < NR) {
                int v = sc[pin][tid];
                if (tid >= d) v += sc[pin][tid - d];
                sc[pin ^ 1][tid] = v;
            }
            __syncthreads();
            pin ^= 1;
        }
        if (tid == 0) s_pre[0] = 0;
        if (tid < NR) s_pre[tid + 1] = sc[pin][tid];
        __syncthreads();
        for (int r = tid; r < NR + 1; r += 256) off[a * (NR + 1) + r] = s_pre[r];
        for (int r = tid; r < NR; r += 256) s_cur[r] = s_pre[r];
        __syncthreads();
#pragma unroll
        for (int k = 0; k < PIX_PT; ++k) {
            int p = tid + k * 256;
            if (p < NPIX) {
                int slot = atomicAdd(&s_cur[rloc[k]], 1);
                list[a * NPIX + slot] = (uint16_t)p;
            }
        }
    } else if (blockIdx.x < NA + TR_BLKS) {
        const int bidx = blockIdx.x - NA;
        const int h    = bidx >> 3;        // 0..25
        const int g    = bidx & 7;         // 0..7
        const int bc0  = g * 16;
        __shared__ float s_row[16][802];
        const float C1 = (float)(288.0 / 26.0);
        const float C2 = (float)(800.0 / 122.0);
        const int hi = (int)floorf((float)h * C1);
        for (int i = tid; i < 16 * 200; i += 256) {
            int j  = i / 200;
            int c4 = i - j * 200;
            const float4* rp = reinterpret_cast<const float4*>(
                pred + ((size_t)(bc0 + j) * PH + hi) * PW);
            float4 v = rp[c4];
            s_row[j][c4 * 4 + 0] = v.x;
            s_row[j][c4 * 4 + 1] = v.y;
            s_row[j][c4 * 4 + 2] = v.z;
            s_row[j][c4 * 4 + 3] = v.w;
        }
        __syncthreads();
        for (int idx = tid; idx < W_HT * 16; idx += 256) {
            int w = idx >> 4;              // 0..121
            int j = idx & 15;
            int wi = (int)floorf((float)w * C2);
            pred_T[(size_t)(h * W_HT + w) * NBC + bc0 + j] = s_row[j][wi];
        }
    } else {
        int bz = blockIdx.x - NA - TR_BLKS;
        int i0 = bz * 256 + tid;
        for (int i = i0; i < NA * NBC; i += ZERO_BLKS * 256) pvp[i] = 0ull;
        if (bz == 0 && tid <= NSHARD) cnt[tid * CNT_STRIDE] = 0u;
    }
}

// ---------------- Kernel B: hough (R18 T7) + L1 + fence-free sharded tail ---
__global__ __launch_bounds__(256) void hough_l1_loss(const float* __restrict__ pred_T,
                                                     const int* __restrict__ off,
                                                     const uint16_t* __restrict__ list,
                                                     unsigned long long* __restrict__ pvp,
                                                     float* __restrict__ L1t,
                                                     unsigned int* __restrict__ cnt,
                                                     const float* __restrict__ ht,
                                                     const float* __restrict__ pexist,
                                                     float* __restrict__ out) {
    __shared__ uint16_t s_list[NPIX];    // 6344 B
    __shared__ int      s_off[NR + 1];
    __shared__ float    s_v[4][32][4];
    __shared__ int      s_i[4][32][4];

    const int tid = threadIdx.x;

    if (blockIdx.x < HB) {
        // ---------- hough float4 quad-lanes (R18-validated, verbatim) ------
        const int blk  = blockIdx.x;
        const int a    = blk / NSPLIT;
        const int q    = blk - a * NSPLIT;
        const int w    = tid >> 6;
        const int lane = tid & 63;
        const int li   = lane & 31;
        const int hw8  = (lane >> 5) * 8;

        {
            const uint32_t* src = reinterpret_cast<const uint32_t*>(list + a * NPIX);
            uint32_t* dst = reinterpret_cast<uint32_t*>(s_list);
            for (int i = tid; i < NPIX / 2; i += 256) dst[i] = src[i];
            for (int r = tid; r < NR + 1; r += 256) s_off[r] = off[a * (NR + 1) + r];
        }
        __syncthreads();

        const float4* pT4 = reinterpret_cast<const float4*>(pred_T);
        float bvx = -1.0f, bvy = -1.0f, bvz = -1.0f, bvw = -1.0f;
        int   bix = 0, biy = 0, biz = 0, biw = 0;
        for (int r = q * 4 + w; r < NR; r += 64) {
            const int o0 = s_off[r];
            const int o1 = s_off[r + 1];
            float4 c0 = {0,0,0,0}, c1 = {0,0,0,0}, c2 = {0,0,0,0}, c3 = {0,0,0,0};
            float4 c4 = {0,0,0,0}, c5 = {0,0,0,0}, c6 = {0,0,0,0}, c7 = {0,0,0,0};
            for (int j = o0; j < o1; j += 16) {
                int base = j + hw8;
                int i0 = base, i1 = base + 1, i2 = base + 2, i3 = base + 3;
                int i4 = base + 4, i5 = base + 5, i6 = base + 6, i7 = base + 7;
                float m0 = (i0 < o1) ? 1.0f : 0.0f;
                float m1 = (i1 < o1) ? 1.0f : 0.0f;
                float m2 = (i2 < o1) ? 1.0f : 0.0f;
                float m3 = (i3 < o1) ? 1.0f : 0.0f;
                float m4 = (i4 < o1) ? 1.0f : 0.0f;
                float m5 = (i5 < o1) ? 1.0f : 0.0f;
                float m6 = (i6 < o1) ? 1.0f : 0.0f;
                float m7 = (i7 < o1) ? 1.0f : 0.0f;
                int p0 = s_list[i0 < o1 ? i0 : o0];
                int p1 = s_list[i1 < o1 ? i1 : o0];
                int p2 = s_list[i2 < o1 ? i2 : o0];
                int p3 = s_list[i3 < o1 ? i3 : o0];
                int p4 = s_list[i4 < o1 ? i4 : o0];
                int p5 = s_list[i5 < o1 ? i5 : o0];
                int p6 = s_list[i6 < o1 ? i6 : o0];
                int p7 = s_list[i7 < o1 ? i7 : o0];
                float4 v0 = pT4[p0 * 32 + li];
                float4 v1 = pT4[p1 * 32 + li];
                float4 v2 = pT4[p2 * 32 + li];
                float4 v3 = pT4[p3 * 32 + li];
                float4 v4 = pT4[p4 * 32 + li];
                float4 v5 = pT4[p5 * 32 + li];
                float4 v6 = pT4[p6 * 32 + li];
                float4 v7 = pT4[p7 * 32 + li];
                c0.x = fmaf(v0.x, m0, c0.x); c0.y = fmaf(v0.y, m0, c0.y);
                c0.z = fmaf(v0.z, m0, c0.z); c0.w = fmaf(v0.w, m0, c0.w);
                c1.x = fmaf(v1.x, m1, c1.x); c1.y = fmaf(v1.y, m1, c1.y);
                c1.z = fmaf(v1.z, m1, c1.z); c1.w = fmaf(v1.w, m1, c1.w);
                c2.x = fmaf(v2.x, m2, c2.x); c2.y = fmaf(v2.y, m2, c2.y);
                c2.z = fmaf(v2.z, m2, c2.z); c2.w = fmaf(v2.w, m2, c2.w);
                c3.x = fmaf(v3.x, m3, c3.x); c3.y = fmaf(v3.y, m3, c3.y);
                c3.z = fmaf(v3.z, m3, c3.z); c3.w = fmaf(v3.w, m3, c3.w);
                c4.x = fmaf(v4.x, m4, c4.x); c4.y = fmaf(v4.y, m4, c4.y);
                c4.z = fmaf(v4.z, m4, c4.z); c4.w = fmaf(v4.w, m4, c4.w);
                c5.x = fmaf(v5.x, m5, c5.x); c5.y = fmaf(v5.y, m5, c5.y);
                c5.z = fmaf(v5.z, m5, c5.z); c5.w = fmaf(v5.w, m5, c5.w);
                c6.x = fmaf(v6.x, m6, c6.x); c6.y = fmaf(v6.y, m6, c6.y);
                c6.z = fmaf(v6.z, m6, c6.z); c6.w = fmaf(v6.w, m6, c6.w);
                c7.x = fmaf(v7.x, m7, c7.x); c7.y = fmaf(v7.y, m7, c7.y);
                c7.z = fmaf(v7.z, m7, c7.z); c7.w = fmaf(v7.w, m7, c7.w);
            }
            float sx = ((c0.x + c1.x) + (c2.x + c3.x)) + ((c4.x + c5.x) + (c6.x + c7.x));
            float sy = ((c0.y + c1.y) + (c2.y + c3.y)) + ((c4.y + c5.y) + (c6.y + c7.y));
            float sz = ((c0.z + c1.z) + (c2.z + c3.z)) + ((c4.z + c5.z) + (c6.z + c7.z));
            float sw = ((c0.w + c1.w) + (c2.w + c3.w)) + ((c4.w + c5.w) + (c6.w + c7.w));
            sx += __shfl_xor(sx, 32);
            sy += __shfl_xor(sy, 32);
            sz += __shfl_xor(sz, 32);
            sw += __shfl_xor(sw, 32);
            int gbin = a * NR + r;
            if (sx > bvx) { bvx = sx; bix = gbin; }
            if (sy > bvy) { bvy = sy; biy = gbin; }
            if (sz > bvz) { bvz = sz; biz = gbin; }
            if (sw > bvw) { bvw = sw; biw = gbin; }
        }
        if (hw8 == 0) {
            s_v[w][li][0] = bvx; s_i[w][li][0] = bix;
            s_v[w][li][1] = bvy; s_i[w][li][1] = biy;
            s_v[w][li][2] = bvz; s_i[w][li][2] = biz;
            s_v[w][li][3] = bvw; s_i[w][li][3] = biw;
        }
        __syncthreads();
        if (tid < 32) {
#pragma unroll
            for (int comp = 0; comp < 4; ++comp) {
                float m = s_v[0][tid][comp];
                int   jb = s_i[0][tid][comp];
#pragma unroll
                for (int ww = 1; ww < 4; ++ww) {
                    float ov = s_v[ww][tid][comp];
                    int   oi = s_i[ww][tid][comp];
                    if (ov > m || (ov == m && oi < jb)) { m = ov; jb = oi; }
                }
                unsigned long long e = ((unsigned long long)__float_as_uint(m < 0.f ? 0.f : m) << 32)
                                     | (unsigned long long)(65535 - jb);
                atomicMax(&pvp[(4 * tid + comp) * NA + a], e);
            }
        }
    } else {
        // ---------- L1 workers: device-coherent atomic stores --------------
        const int i = blockIdx.x - HB;
        for (int e = i * 256 + tid; e < NBC * NR; e += L1_BLKS * 256) {
            int cr = e / NR;               // (b*4+c)
            int r  = e - cr * NR;
            const float* base = ht + (size_t)cr * NA * NR + r;
            float s = 0.0f;
            for (int a = 0; a < NA; ++a) s += fabsf(base[a * NR]);
            atomicExch(&L1t[e], s);        // coherent-point write, no fence
        }
    }

    // ---- fence-free sharded arrival: vmcnt drain, 2-level counters ----
    __shared__ int s_last;
    asm volatile("s_waitcnt vmcnt(0)" ::: "memory");  // atomics complete @ coherent point
    __syncthreads();
    if (tid == 0) {
        int last = 0;
        int shard = blockIdx.x / SHARD_SZ;            // 0..NSHARD-1, exact
        unsigned int o1 = atomicAdd(&cnt[shard * CNT_STRIDE], 1u);
        if (o1 == (unsigned int)(SHARD_SZ - 1)) {
            unsigned int o2 = atomicAdd(&cnt[NSHARD * CNT_STRIDE], 1u);
            last = (o2 == (unsigned int)(NSHARD - 1)) ? 1 : 0;
        }
        s_last = last;
    }
    __syncthreads();
    if (!s_last) return;
    __threadfence();   // tail-only acquire (single block, cheap)

    __shared__ int   s_fidx[NBC];
    __shared__ float s_t[512];

    if (tid < NBC) {   // per (b,k): argmax over 60 angles (packed-u64 max)
        unsigned long long be = 0ull;
        const unsigned long long* pr = pvp + (size_t)tid * NA;
        for (int aa = 0; aa < NA; ++aa) {
            unsigned long long e = pr[aa];
            if (e > be) be = e;
        }
        s_fidx[tid] = 65535 - (int)(be & 0xFFFFull);
    }
    __syncthreads();

#pragma unroll
    for (int it = 0; it < 2; ++it) {
        int T = tid + 256 * it;           // task = (b, c, k)
        int b = T >> 4;
        int combo = T & 15;
        int c = combo >> 2;
        int k = combo & 3;
        int fidx = s_fidx[b * 4 + k];
        int a0 = fidx / NR;
        int r  = fidx - a0 * NR;
        int cr = b * 4 + c;
        float l1 = fmaxf(L1t[cr * NR + r], 1e-12f);
        float gg = ht[((size_t)cr * NA + a0) * NR + r] / l1;
        float ex = (pexist[b * 4 + k] > 0.9f) ? 1.0f : 0.0f;
        s_t[T] = -logf(gg + 1e-12f) * ex;
    }
    __syncthreads();
    if (tid < NB) {    // deterministic per-b serial 16-sum
        float s = 0.0f;
        for (int i2 = 0; i2 < 16; ++i2) s += s_t[tid * 16 + i2];
        out[tid] = s * (1.0f / 16.0f);
    }
}

extern "C" void kernel_launch(void* const* d_in, const int* in_sizes, int n_in,
                              void* d_out, int out_size, void* d_ws, size_t ws_size,
                              hipStream_t stream) {
    const float* ht     = (const float*)d_in[0];
    const float* pred   = (const float*)d_in[1];
    const float* pexist = (const float*)d_in[2];

    char* ws = (char*)d_ws;
    int*      off    = (int*)     (ws + WS_OFF);
    uint16_t* list   = (uint16_t*)(ws + WS_LIST);
    float*    pred_T = (float*)   (ws + WS_PREDT);
    unsigned long long* pvp = (unsigned long long*)(ws + WS_PVP);
    float*    L1t    = (float*)   (ws + WS_L1);
    unsigned int* cnt = (unsigned int*)(ws + WS_CNT);

    setup<<<NA + TR_BLKS + ZERO_BLKS, 256, 0, stream>>>(pred, off, list, pred_T, pvp, cnt);
    hough_l1_loss<<<K2_BLKS, 256, 0, stream>>>(pred_T, off, list, pvp, L1t, cnt,
                                               ht, pexist, (float*)d_out);
}

// Round 25
// 30.062 us; speedup vs baseline: 3.8196x; 1.0413x over previous
//
#include <hip/hip_runtime.h>
#include <hip/hip_bf16.h>
#include <stdint.h>
#include <math.h>

#define H_HT 26
#define W_HT 122
#define NPIX (H_HT * W_HT)   // 3172
#define NA 60
#define NR 125
#define NB 32
#define NC 4
#define NBC (NB * NC)        // 128
#define PH 288
#define PW 800
#define NSPLIT 16            // rho splits per angle; wave bins r = q*4+w + 64t
#define PIX_PT 13            // ceil(3172/256) pixels per thread in csr

#define TR_BLKS (H_HT * 8)               // 208 transpose blocks: (h, 16-bc group)
#define ZERO_BLKS 4

// ---- workspace layout (bytes) ----
#define WS_OFF   190336                    // int32 [60*126]          30240
#define WS_LIST  220608                    // uint16[60*3172]        380640
#define WS_PREDT 601280                    // float [3172*128]      1624064
#define WS_PVP   2225344                   // u64   [128*60]          61440

// ---------------- Kernel A: fused setup (R14-validated, byte-identical) -----
__global__ __launch_bounds__(256) void setup(const float* __restrict__ pred,
                                             int* __restrict__ off,
                                             uint16_t* __restrict__ list,
                                             float* __restrict__ pred_T,
                                             unsigned long long* __restrict__ pvp) {
    const int tid = threadIdx.x;
    if (blockIdx.x < NA) {
        const int a = blockIdx.x;
        __shared__ int s_cnt[NR];
        __shared__ int sc[2][NR];
        __shared__ int s_pre[NR + 1];
        __shared__ int s_cur[NR];

        double t  = __dmul_rn((double)(a * 3), 0.017453292519943295);
        double cs = cos(t);
        double sn = sin(t);

        int rloc[PIX_PT];
#pragma unroll
        for (int k = 0; k < PIX_PT; ++k) {
            int p = tid + k * 256;
            rloc[k] = 0;
            if (p < NPIX) {
                int h = p / W_HT;
                int w = p - h * W_HT;
                double xs = (double)w - 60.5;
                double ys = (double)h - 12.5;
                double rho = __dadd_rn(__dmul_rn(xs, cs), __dmul_rn(ys, sn));
                int r = (int)rint(rho) + NR / 2;
                r = r < 0 ? 0 : (r > NR - 1 ? NR - 1 : r);
                rloc[k] = r;
            }
        }
        for (int i = tid; i < NR; i += 256) s_cnt[i] = 0;
        __syncthreads();
#pragma unroll
        for (int k = 0; k < PIX_PT; ++k) {
            int p = tid + k * 256;
            if (p < NPIX) atomicAdd(&s_cnt[rloc[k]], 1);
        }
        __syncthreads();
        if (tid < NR) sc[0][tid] = s_cnt[tid];
        __syncthreads();
        int pin = 0;
        for (int d = 1; d < NR; d <<= 1) {
            if (tid < NR) {
                int v = sc[pin][tid];
                if (tid >= d) v += sc[pin][tid - d];
                sc[pin ^ 1][tid] = v;
            }
            __syncthreads();
            pin ^= 1;
        }
        if (tid == 0) s_pre[0] = 0;
        if (tid < NR) s_pre[tid + 1] = sc[pin][tid];
        __syncthreads();
        for (int r = tid; r < NR + 1; r += 256) off[a * (NR + 1) + r] = s_pre[r];
        for (int r = tid; r < NR; r += 256) s_cur[r] = s_pre[r];
        __syncthreads();
#pragma unroll
        for (int k = 0; k < PIX_PT; ++k) {
            int p = tid + k * 256;
            if (p < NPIX) {
                int slot = atomicAdd(&s_cur[rloc[k]], 1);
                list[a * NPIX + slot] = (uint16_t)p;
            }
        }
    } else if (blockIdx.x < NA + TR_BLKS) {
        const int bidx = blockIdx.x - NA;
        const int h    = bidx >> 3;        // 0..25
        const int g    = bidx & 7;         // 0..7
        const int bc0  = g * 16;
        __shared__ float s_row[16][802];
        const float C1 = (float)(288.0 / 26.0);
        const float C2 = (float)(800.0 / 122.0);
        const int hi = (int)floorf((float)h * C1);
        for (int i = tid; i < 16 * 200; i += 256) {
            int j  = i / 200;
            int c4 = i - j * 200;
            const float4* rp = reinterpret_cast<const float4*>(
                pred + ((size_t)(bc0 + j) * PH + hi) * PW);
            float4 v = rp[c4];
            s_row[j][c4 * 4 + 0] = v.x;
            s_row[j][c4 * 4 + 1] = v.y;
            s_row[j][c4 * 4 + 2] = v.z;
            s_row[j][c4 * 4 + 3] = v.w;
        }
        __syncthreads();
        for (int idx = tid; idx < W_HT * 16; idx += 256) {
            int w = idx >> 4;              // 0..121
            int j = idx & 15;
            int wi = (int)floorf((float)w * C2);
            pred_T[(size_t)(h * W_HT + w) * NBC + bc0 + j] = s_row[j][wi];
        }
    } else {
        int bz = blockIdx.x - NA - TR_BLKS;
        int i0 = bz * 256 + tid;
        for (int i = i0; i < NA * NBC; i += ZERO_BLKS * 256) pvp[i] = 0ull;
    }
}

// ---------------- Kernel B: hough, float4 quad-lanes + half-wave split ------
__global__ __launch_bounds__(256) void hough_T7(const float* __restrict__ pred_T,
                                                const int* __restrict__ off,
                                                const uint16_t* __restrict__ list,
                                                unsigned long long* __restrict__ pvp) {
    __shared__ uint16_t s_list[NPIX];    // 6344 B
    __shared__ int      s_off[NR + 1];
    __shared__ float    s_v[4][32][4];
    __shared__ int      s_i[4][32][4];

    const int blk  = blockIdx.x;
    const int a    = blk / NSPLIT;
    const int q    = blk - a * NSPLIT;
    const int tid  = threadIdx.x;
    const int w    = tid >> 6;
    const int lane = tid & 63;
    const int li   = lane & 31;
    const int hw8  = (lane >> 5) * 8;

    {   // stage full angle list (coalesced as uint32) + offsets
        const uint32_t* src = reinterpret_cast<const uint32_t*>(list + a * NPIX);
        uint32_t* dst = reinterpret_cast<uint32_t*>(s_list);
        for (int i = tid; i < NPIX / 2; i += 256) dst[i] = src[i];
        for (int r = tid; r < NR + 1; r += 256) s_off[r] = off[a * (NR + 1) + r];
    }
    __syncthreads();

    const float4* pT4 = reinterpret_cast<const float4*>(pred_T);
    float bvx = -1.0f, bvy = -1.0f, bvz = -1.0f, bvw = -1.0f;
    int   bix = 0, biy = 0, biz = 0, biw = 0;
    for (int r = q * 4 + w; r < NR; r += 64) {
        const int o0 = s_off[r];
        const int o1 = s_off[r + 1];
        float4 c0 = {0,0,0,0}, c1 = {0,0,0,0}, c2 = {0,0,0,0}, c3 = {0,0,0,0};
        float4 c4 = {0,0,0,0}, c5 = {0,0,0,0}, c6 = {0,0,0,0}, c7 = {0,0,0,0};
        for (int j = o0; j < o1; j += 16) {
            int base = j + hw8;
            int i0 = base, i1 = base + 1, i2 = base + 2, i3 = base + 3;
            int i4 = base + 4, i5 = base + 5, i6 = base + 6, i7 = base + 7;
            float m0 = (i0 < o1) ? 1.0f : 0.0f;
            float m1 = (i1 < o1) ? 1.0f : 0.0f;
            float m2 = (i2 < o1) ? 1.0f : 0.0f;
            float m3 = (i3 < o1) ? 1.0f : 0.0f;
            float m4 = (i4 < o1) ? 1.0f : 0.0f;
            float m5 = (i5 < o1) ? 1.0f : 0.0f;
            float m6 = (i6 < o1) ? 1.0f : 0.0f;
            float m7 = (i7 < o1) ? 1.0f : 0.0f;
            int p0 = s_list[i0 < o1 ? i0 : o0];
            int p1 = s_list[i1 < o1 ? i1 : o0];
            int p2 = s_list[i2 < o1 ? i2 : o0];
            int p3 = s_list[i3 < o1 ? i3 : o0];
            int p4 = s_list[i4 < o1 ? i4 : o0];
            int p5 = s_list[i5 < o1 ? i5 : o0];
            int p6 = s_list[i6 < o1 ? i6 : o0];
            int p7 = s_list[i7 < o1 ? i7 : o0];
            float4 v0 = pT4[p0 * 32 + li];
            float4 v1 = pT4[p1 * 32 + li];
            float4 v2 = pT4[p2 * 32 + li];
            float4 v3 = pT4[p3 * 32 + li];
            float4 v4 = pT4[p4 * 32 + li];
            float4 v5 = pT4[p5 * 32 + li];
            float4 v6 = pT4[p6 * 32 + li];
            float4 v7 = pT4[p7 * 32 + li];
            c0.x = fmaf(v0.x, m0, c0.x); c0.y = fmaf(v0.y, m0, c0.y);
            c0.z = fmaf(v0.z, m0, c0.z); c0.w = fmaf(v0.w, m0, c0.w);
            c1.x = fmaf(v1.x, m1, c1.x); c1.y = fmaf(v1.y, m1, c1.y);
            c1.z = fmaf(v1.z, m1, c1.z); c1.w = fmaf(v1.w, m1, c1.w);
            c2.x = fmaf(v2.x, m2, c2.x); c2.y = fmaf(v2.y, m2, c2.y);
            c2.z = fmaf(v2.z, m2, c2.z); c2.w = fmaf(v2.w, m2, c2.w);
            c3.x = fmaf(v3.x, m3, c3.x); c3.y = fmaf(v3.y, m3, c3.y);
            c3.z = fmaf(v3.z, m3, c3.z); c3.w = fmaf(v3.w, m3, c3.w);
            c4.x = fmaf(v4.x, m4, c4.x); c4.y = fmaf(v4.y, m4, c4.y);
            c4.z = fmaf(v4.z, m4, c4.z); c4.w = fmaf(v4.w, m4, c4.w);
            c5.x = fmaf(v5.x, m5, c5.x); c5.y = fmaf(v5.y, m5, c5.y);
            c5.z = fmaf(v5.z, m5, c5.z); c5.w = fmaf(v5.w, m5, c5.w);
            c6.x = fmaf(v6.x, m6, c6.x); c6.y = fmaf(v6.y, m6, c6.y);
            c6.z = fmaf(v6.z, m6, c6.z); c6.w = fmaf(v6.w, m6, c6.w);
            c7.x = fmaf(v7.x, m7, c7.x); c7.y = fmaf(v7.y, m7, c7.y);
            c7.z = fmaf(v7.z, m7, c7.z); c7.w = fmaf(v7.w, m7, c7.w);
        }
        float sx = ((c0.x + c1.x) + (c2.x + c3.x)) + ((c4.x + c5.x) + (c6.x + c7.x));
        float sy = ((c0.y + c1.y) + (c2.y + c3.y)) + ((c4.y + c5.y) + (c6.y + c7.y));
        float sz = ((c0.z + c1.z) + (c2.z + c3.z)) + ((c4.z + c5.z) + (c6.z + c7.z));
        float sw = ((c0.w + c1.w) + (c2.w + c3.w)) + ((c4.w + c5.w) + (c6.w + c7.w));
        sx += __shfl_xor(sx, 32);
        sy += __shfl_xor(sy, 32);
        sz += __shfl_xor(sz, 32);
        sw += __shfl_xor(sw, 32);
        int gbin = a * NR + r;
        if (sx > bvx) { bvx = sx; bix = gbin; }
        if (sy > bvy) { bvy = sy; biy = gbin; }
        if (sz > bvz) { bvz = sz; biz = gbin; }
        if (sw > bvw) { bvw = sw; biw = gbin; }
    }
    if (hw8 == 0) {
        s_v[w][li][0] = bvx; s_i[w][li][0] = bix;
        s_v[w][li][1] = bvy; s_i[w][li][1] = biy;
        s_v[w][li][2] = bvz; s_i[w][li][2] = biz;
        s_v[w][li][3] = bvw; s_i[w][li][3] = biw;
    }
    __syncthreads();
    if (tid < 32) {
#pragma unroll
        for (int comp = 0; comp < 4; ++comp) {
            float m = s_v[0][tid][comp];
            int   jb = s_i[0][tid][comp];
#pragma unroll
            for (int ww = 1; ww < 4; ++ww) {
                float ov = s_v[ww][tid][comp];
                int   oi = s_i[ww][tid][comp];
                if (ov > m || (ov == m && oi < jb)) { m = ov; jb = oi; }
            }
            unsigned long long e = ((unsigned long long)__float_as_uint(m < 0.f ? 0.f : m) << 32)
                                 | (unsigned long long)(65535 - jb);
            atomicMax(&pvp[(4 * tid + comp) * NA + a], e);
        }
    }
}

// ---------------- Kernel C: final argmax + gather + L1-normalize + loss -----
__global__ __launch_bounds__(256) void loss4(const float* __restrict__ ht,
                                             const float* __restrict__ pexist,
                                             const unsigned long long* __restrict__ pvp,
                                             float* __restrict__ out) {
    __shared__ float s_sum[4];
    const int b    = blockIdx.x;
    const int tid  = threadIdx.x;
    const int k    = tid >> 6;      // wave = idx/exist channel
    const int lane = tid & 63;
    const int c    = lane >> 4;     // ht channel
    const int s    = lane & 15;

    unsigned long long be = 0ull;
    if (lane < NA) be = pvp[(b * 4 + k) * NA + lane];
#pragma unroll
    for (int m = 32; m > 0; m >>= 1) {
        unsigned long long oe = __shfl_xor(be, m);
        if (oe > be) be = oe;
    }
    int fidx = 65535 - (int)(be & 0xFFFFull);
    int a0 = fidx / NR;
    int r  = fidx - a0 * NR;

    const float* htc = ht + (size_t)((b * 4 + c) * NA) * NR;
    float acc = 0.0f;
#pragma unroll
    for (int t = 0; t < 4; ++t) {
        int a = s + t * 16;
        if (a < NA) acc += fabsf(htc[a * NR + r]);
    }
#pragma unroll
    for (int m = 1; m < 16; m <<= 1) acc += __shfl_xor(acc, m);

    float term = 0.0f;
    if (s == 0) {
        float l1 = fmaxf(acc, 1e-12f);
        float gg = htc[a0 * NR + r] / l1;
        float ex = (pexist[b * 4 + k] > 0.9f) ? 1.0f : 0.0f;
        term = -logf(gg + 1e-12f) * ex;
    }
#pragma unroll
    for (int m = 16; m < 64; m <<= 1) term += __shfl_xor(term, m);
    if (lane == 0) s_sum[k] = term;
    __syncthreads();
    if (tid == 0)
        out[b] = (s_sum[0] + s_sum[1] + s_sum[2] + s_sum[3]) * (1.0f / 16.0f);
}

extern "C" void kernel_launch(void* const* d_in, const int* in_sizes, int n_in,
                              void* d_out, int out_size, void* d_ws, size_t ws_size,
                              hipStream_t stream) {
    const float* ht     = (const float*)d_in[0];
    const float* pred   = (const float*)d_in[1];
    const float* pexist = (const float*)d_in[2];

    char* ws = (char*)d_ws;
    int*      off    = (int*)     (ws + WS_OFF);
    uint16_t* list   = (uint16_t*)(ws + WS_LIST);
    float*    pred_T = (float*)   (ws + WS_PREDT);
    unsigned long long* pvp = (unsigned long long*)(ws + WS_PVP);

    setup<<<NA + TR_BLKS + ZERO_BLKS, 256, 0, stream>>>(pred, off, list, pred_T, pvp);
    hough_T7<<<NA * NSPLIT, 256, 0, stream>>>(pred_T, off, list, pvp);
    loss4<<<NB, 256, 0, stream>>>(ht, pexist, pvp, (float*)d_out);
}